// Round 7
// baseline (41369.092 us; speedup 1.0000x reference)
//
#include <hip/hip_runtime.h>
#include <hip/hip_bf16.h>
#include <hip/hip_fp16.h>

// Model dims
#define BB 64
#define TT 512
#define DD 512
#define EE 6
#define PP 96
#define NHH 4
#define HDD 128
#define FFF 2048

typedef short bf16x8 __attribute__((ext_vector_type(8)));
typedef float f32x4 __attribute__((ext_vector_type(4)));

__device__ __forceinline__ float bf2f(unsigned short u) {
    unsigned int x = ((unsigned int)u) << 16;
    return __uint_as_float(x);
}
__device__ __forceinline__ unsigned short f2bf(float f) {
    __hip_bfloat16 h = __float2bfloat16(f);
    return *reinterpret_cast<unsigned short*>(&h);
}

// ---------------------------------------------------------------------------
// Generic MFMA GEMM:  C[m][n] = alpha * sum_k A[m][k] * W[n][k]  (+bias[n])
// 128x128 tile, BK=32, 256 threads (4 waves, each a 64x64 quadrant of
// 4x4 mfma_f32_16x16x32_bf16). TRANSW stages W[k*ldw+n] (V^T for P·V).
// Batched via blockIdx.z -> (b = z/Hdiv, h = z%Hdiv) offsets.
// ---------------------------------------------------------------------------
template<bool TRANSW, bool BIAS, bool RELU, bool OUTBF16>
__global__ __launch_bounds__(256) void gemm_bt(
    const unsigned short* __restrict__ A, int lda, long long aB, long long aH,
    const unsigned short* __restrict__ W, int ldw, long long wB, long long wH,
    const float* __restrict__ bias,
    void* __restrict__ Cv, int ldc, long long cB, long long cH,
    int K, int Hdiv, float alpha)
{
    __shared__ unsigned short As[128 * 40];
    __shared__ unsigned short Ws[128 * 40];
    int t = threadIdx.x;
    int z = blockIdx.z;
    int zb = z / Hdiv, zh = z - zb * Hdiv;
    long long aOff = (long long)zb * aB + (long long)zh * aH;
    long long wOff = (long long)zb * wB + (long long)zh * wH;
    long long cOff = (long long)zb * cB + (long long)zh * cH;
    int m0 = blockIdx.x * 128, n0 = blockIdx.y * 128;

    int arow = t >> 1, acol = (t & 1) * 16;
    const unsigned short* Ag = A + aOff + (long long)(m0 + arow) * lda + acol;
    const unsigned short* WgN = W + wOff + (long long)(n0 + arow) * ldw + acol;
    int wk = t >> 3, wn = (t & 7) * 16;
    const unsigned short* WgT = W + wOff + n0 + wn;

    int wave = t >> 6, lane = t & 63;
    int wm = (wave & 1) * 64, wn2 = (wave >> 1) * 64;
    int lrow = lane & 15, quad = lane >> 4;

    f32x4 acc[4][4];
    #pragma unroll
    for (int i = 0; i < 4; i++)
        #pragma unroll
        for (int j = 0; j < 4; j++)
            acc[i][j] = (f32x4){0.f, 0.f, 0.f, 0.f};

    for (int k0 = 0; k0 < K; k0 += 32) {
        __syncthreads();
        {
            uint4 a0 = *(const uint4*)(Ag + k0);
            uint4 a1 = *(const uint4*)(Ag + k0 + 8);
            *(uint4*)&As[arow * 40 + acol] = a0;
            *(uint4*)&As[arow * 40 + acol + 8] = a1;
            if (!TRANSW) {
                uint4 w0 = *(const uint4*)(WgN + k0);
                uint4 w1 = *(const uint4*)(WgN + k0 + 8);
                *(uint4*)&Ws[arow * 40 + acol] = w0;
                *(uint4*)&Ws[arow * 40 + acol + 8] = w1;
            } else {
                const unsigned short* p = WgT + (long long)(k0 + wk) * ldw;
                uint4 w0 = *(const uint4*)(p);
                uint4 w1 = *(const uint4*)(p + 8);
                const unsigned short* s0 = (const unsigned short*)&w0;
                const unsigned short* s1 = (const unsigned short*)&w1;
                #pragma unroll
                for (int j = 0; j < 8; j++) Ws[(wn + j) * 40 + wk] = s0[j];
                #pragma unroll
                for (int j = 0; j < 8; j++) Ws[(wn + 8 + j) * 40 + wk] = s1[j];
            }
        }
        __syncthreads();
        bf16x8 af[4], bf[4];
        #pragma unroll
        for (int i = 0; i < 4; i++)
            af[i] = *(const bf16x8*)&As[(wm + i * 16 + lrow) * 40 + quad * 8];
        #pragma unroll
        for (int j = 0; j < 4; j++)
            bf[j] = *(const bf16x8*)&Ws[(wn2 + j * 16 + lrow) * 40 + quad * 8];
        #pragma unroll
        for (int i = 0; i < 4; i++)
            #pragma unroll
            for (int j = 0; j < 4; j++)
                acc[i][j] = __builtin_amdgcn_mfma_f32_16x16x32_bf16(af[i], bf[j], acc[i][j], 0, 0, 0);
    }

    #pragma unroll
    for (int i = 0; i < 4; i++) {
        #pragma unroll
        for (int j = 0; j < 4; j++) {
            #pragma unroll
            for (int r = 0; r < 4; r++) {
                int row = m0 + wm + i * 16 + quad * 4 + r;
                int col = n0 + wn2 + j * 16 + lrow;
                float v = acc[i][j][r] * alpha;
                if (BIAS) v += bias[col];
                if (RELU) v = fmaxf(v, 0.f);
                long long idx = cOff + (long long)row * ldc + col;
                if (OUTBF16) ((unsigned short*)Cv)[idx] = f2bf(v);
                else         ((float*)Cv)[idx] = v;
            }
        }
    }
}

// ---------------------------------------------------------------------------
__global__ void cvt_k(const float* __restrict__ in, unsigned short* __restrict__ out, int n)
{
    int i = blockIdx.x * 256 + threadIdx.x;
    int stride = gridDim.x * 256;
    for (; i < n; i += stride) out[i] = f2bf(in[i]);
}

// ---------------------------------------------------------------------------
// Build LSTM weight tensor WQ (fp16, d-major):
//   WQ half2 index (d*256 + kk)*4 + g  = ( w_hh[(g*512+d)*512 + 2kk],
//                                          w_hh[(g*512+d)*512 + 2kk+1] )
// One thread per output half2 (writes coalesced; reads L2-cached).
// ---------------------------------------------------------------------------
__global__ __launch_bounds__(256) void wq_prep_k(
    const float* __restrict__ w_hh, __half2* __restrict__ wq)
{
    int id = blockIdx.x * 256 + threadIdx.x;   // 0 .. 512*256*4-1
    int g = id & 3;
    int kk = (id >> 2) & 255;
    int d = id >> 10;
    const float* src = w_hh + ((long long)g * 512 + d) * 512 + 2 * kk;
    wq[id] = __floats2half2_rn(src[0], src[1]);
}

// ---------------------------------------------------------------------------
// GARCH: per-batch variance + 511-step scalar recurrence. 1 block, lane = batch.
// ---------------------------------------------------------------------------
__global__ __launch_bounds__(64) void garch_k(
    const float* __restrict__ xe, const float* __restrict__ omega,
    const float* __restrict__ alpha, const float* __restrict__ beta,
    float* __restrict__ vol)
{
    int b = threadIdx.x;
    float sm = 0.f, sq = 0.f;
    for (int t2 = 0; t2 < TT; t2++) {
        float r = xe[((long long)b * TT + t2) * EE + 5];
        sm += r; sq += r * r;
    }
    float mean = sm / 512.f;
    float var = (sq - 512.f * mean * mean) / 511.f;
    float h = var + 1e-6f;
    float om = log1pf(expf(omega[0]));
    float al = 0.2f / (1.f + expf(-alpha[0]));
    float be = 0.8f / (1.f + expf(-beta[0]));
    for (int t2 = 0; t2 < TT - 1; t2++) {
        float r = xe[((long long)b * TT + t2) * EE + 5];
        h = om + al * r * r + be * h;
    }
    vol[b] = sqrtf(h);
}

// ---------------------------------------------------------------------------
// Batch-parallel LSTM: ONE launch, 64 blocks (= batches) x 512 threads
// (= hidden dims). All 512 timesteps inside the kernel; the only sync is
// block-local __syncthreads (batch chains are independent -- no grid sync).
// Thread d owns dim d and all 4 gates: 4 x __hfma2 per packed k-pair, no
// cross-thread reduction. h lives in LDS as fp16 (broadcast ds_read_b128);
// c in a register (fp32). Weights: fp16 WQ, d-major so the 256 inner loads
// are base + imm-offset (0..4080). fp16 products are flushed to fp32
// accumulators every 64 k to bound accumulation error. Writes XB (b,t,d)
// bf16 directly (kills the old transpose kernel).
// Per-step cost model: BW 128 MB/step L2 ~3.7us | VALU ~2us | LDS ~2.6us.
// ---------------------------------------------------------------------------
__global__ __launch_bounds__(512) void lstm_batch_k(
    const float* __restrict__ xe, const unsigned short* __restrict__ wq,
    const float* __restrict__ w_ih, const float* __restrict__ b_ih,
    const float* __restrict__ b_hh,
    unsigned short* __restrict__ XB_)
{
    int b = blockIdx.x;
    int d = threadIdx.x;

    __shared__ __align__(16) __half h_s[512];

    float wi[4][6];
    float bias[4];
    #pragma unroll
    for (int g = 0; g < 4; g++) {
        #pragma unroll
        for (int e = 0; e < 6; e++) wi[g][e] = w_ih[((long long)g * 512 + d) * 6 + e];
        bias[g] = b_ih[g * 512 + d] + b_hh[g * 512 + d];
    }
    float c = 0.f;
    h_s[d] = __float2half_rn(0.f);
    __syncthreads();

    // per-thread weight row: 256 x 16B contiguous
    const unsigned short* wrow = wq + (long long)d * 2048;   // 256 kk * 8 ushort

    const float* xb = xe + (long long)b * TT * EE;
    unsigned short* ob = XB_ + (long long)b * TT * DD + d;

    for (int t = 0; t < 512; t++) {
        float acc0 = 0.f, acc1 = 0.f, acc2 = 0.f, acc3 = 0.f;
        // 8 groups x 32 k2 (64 k each), fp16 inner acc -> fp32 flush
        #pragma unroll 1
        for (int grp = 0; grp < 8; grp++) {
            __half2 ha0 = __float2half2_rn(0.f);
            __half2 ha1 = ha0, ha2 = ha0, ha3 = ha0;
            const unsigned short* wg = wrow + grp * 256;   // 32 kk * 8
            const uint4* hp = (const uint4*)&h_s[grp * 64];
            #pragma unroll
            for (int cc = 0; cc < 8; cc++) {
                uint4 hraw = hp[cc];                       // 8 halves = 4 pairs
                const __half2* hh = (const __half2*)&hraw;
                #pragma unroll
                for (int j = 0; j < 4; j++) {
                    uint4 wraw = *(const uint4*)(wg + (cc * 4 + j) * 8);
                    const __half2* ww = (const __half2*)&wraw;
                    ha0 = __hfma2(ww[0], hh[j], ha0);
                    ha1 = __hfma2(ww[1], hh[j], ha1);
                    ha2 = __hfma2(ww[2], hh[j], ha2);
                    ha3 = __hfma2(ww[3], hh[j], ha3);
                }
            }
            float2 f0 = __half22float2(ha0); acc0 += f0.x + f0.y;
            float2 f1 = __half22float2(ha1); acc1 += f1.x + f1.y;
            float2 f2 = __half22float2(ha2); acc2 += f2.x + f2.y;
            float2 f3 = __half22float2(ha3); acc3 += f3.x + f3.y;
        }

        const float* xr = xb + t * EE;
        float x0 = xr[0], x1 = xr[1], x2 = xr[2], x3 = xr[3], x4 = xr[4], x5 = xr[5];
        float pi = acc0 + bias[0] + x0*wi[0][0] + x1*wi[0][1] + x2*wi[0][2] + x3*wi[0][3] + x4*wi[0][4] + x5*wi[0][5];
        float pf = acc1 + bias[1] + x0*wi[1][0] + x1*wi[1][1] + x2*wi[1][2] + x3*wi[1][3] + x4*wi[1][4] + x5*wi[1][5];
        float pg = acc2 + bias[2] + x0*wi[2][0] + x1*wi[2][1] + x2*wi[2][2] + x3*wi[2][3] + x4*wi[2][4] + x5*wi[2][5];
        float po = acc3 + bias[3] + x0*wi[3][0] + x1*wi[3][1] + x2*wi[3][2] + x3*wi[3][3] + x4*wi[3][4] + x5*wi[3][5];
        float ig = 1.f / (1.f + __expf(-pi));
        float fg = 1.f / (1.f + __expf(-pf));
        float gg = tanhf(pg);
        float og = 1.f / (1.f + __expf(-po));
        c = fg * c + ig * gg;
        float hn = og * tanhf(c);

        __syncthreads();                 // all reads of h_s(t) done
        h_s[d] = __float2half_rn(hn);
        ob[t * DD] = f2bf(hn);
        __syncthreads();                 // h_s(t+1) visible
    }
}

// ---------------------------------------------------------------------------
// Softmax over last dim (512), in-place on bf16 scores. One wave per row.
// ---------------------------------------------------------------------------
__global__ __launch_bounds__(256) void softmax_k(unsigned short* __restrict__ S)
{
    long long row = (long long)blockIdx.x * 4 + (threadIdx.x >> 6);
    int lane = threadIdx.x & 63;
    unsigned short* p = S + row * 512 + lane * 8;
    uint4 raw = *(const uint4*)p;
    unsigned short* u = (unsigned short*)&raw;
    float v[8];
    float m = -1e30f;
    #pragma unroll
    for (int j = 0; j < 8; j++) { v[j] = bf2f(u[j]); m = fmaxf(m, v[j]); }
    #pragma unroll
    for (int off = 1; off < 64; off <<= 1) m = fmaxf(m, __shfl_xor(m, off));
    float s = 0.f;
    #pragma unroll
    for (int j = 0; j < 8; j++) { v[j] = __expf(v[j] - m); s += v[j]; }
    #pragma unroll
    for (int off = 1; off < 64; off <<= 1) s += __shfl_xor(s, off);
    float inv = 1.f / s;
    unsigned int pk[4];
    #pragma unroll
    for (int j = 0; j < 4; j++)
        pk[j] = (unsigned int)f2bf(v[2 * j] * inv) | ((unsigned int)f2bf(v[2 * j + 1] * inv) << 16);
    *(uint4*)p = make_uint4(pk[0], pk[1], pk[2], pk[3]);
}

// ---------------------------------------------------------------------------
// Residual + LayerNorm: XB = LN(XB + Y)*g + b  (bf16 residual stream).
// ---------------------------------------------------------------------------
__global__ __launch_bounds__(256) void ln_k(
    unsigned short* XB_, const float* __restrict__ Y_,
    const float* __restrict__ g, const float* __restrict__ b2)
{
    long long row = (long long)blockIdx.x * 4 + (threadIdx.x >> 6);
    int lane = threadIdx.x & 63;
    long long base = row * 512 + lane * 8;
    float s[8];
    {
        uint4 xr = *(const uint4*)&XB_[base];
        const unsigned short* xu = (const unsigned short*)&xr;
        float4 y0 = *(const float4*)&Y_[base];
        float4 y1 = *(const float4*)&Y_[base + 4];
        s[0] = bf2f(xu[0]) + y0.x; s[1] = bf2f(xu[1]) + y0.y;
        s[2] = bf2f(xu[2]) + y0.z; s[3] = bf2f(xu[3]) + y0.w;
        s[4] = bf2f(xu[4]) + y1.x; s[5] = bf2f(xu[5]) + y1.y;
        s[6] = bf2f(xu[6]) + y1.z; s[7] = bf2f(xu[7]) + y1.w;
    }
    float sm = 0.f, sq = 0.f;
    #pragma unroll
    for (int j = 0; j < 8; j++) { sm += s[j]; sq += s[j] * s[j]; }
    #pragma unroll
    for (int off = 1; off < 64; off <<= 1) {
        sm += __shfl_xor(sm, off);
        sq += __shfl_xor(sq, off);
    }
    float mean = sm * (1.f / 512.f);
    float var = sq * (1.f / 512.f) - mean * mean;
    float rstd = rsqrtf(var + 1e-5f);
    int col = lane * 8;
    float o[8];
    #pragma unroll
    for (int j = 0; j < 8; j++) o[j] = (s[j] - mean) * rstd * g[col + j] + b2[col + j];
    unsigned int pk[4];
    #pragma unroll
    for (int j = 0; j < 4; j++)
        pk[j] = (unsigned int)f2bf(o[2 * j]) | ((unsigned int)f2bf(o[2 * j + 1]) << 16);
    *(uint4*)&XB_[base] = make_uint4(pk[0], pk[1], pk[2], pk[3]);
}

// ---------------------------------------------------------------------------
// Heads: garch_base + gate * ai_residual. One block per batch.
// ---------------------------------------------------------------------------
__global__ __launch_bounds__(128) void head_k(
    const unsigned short* __restrict__ XB_, const float* __restrict__ xe,
    const float* __restrict__ vol,
    const float* __restrict__ rh_w, const float* __restrict__ rh_b,
    const float* __restrict__ g1_w, const float* __restrict__ g1_b,
    const float* __restrict__ g2_w, const float* __restrict__ g2_b,
    const float* __restrict__ gp_w, const float* __restrict__ gp_b,
    float* __restrict__ out)
{
    int b = blockIdx.x, t = threadIdx.x;
    __shared__ float xl[512];
    __shared__ float hid[256];
    for (int j = t; j < 512; j += 128)
        xl[j] = bf2f(XB_[((long long)b * TT + (TT - 1)) * DD + j]);
    float gin[7];
    #pragma unroll
    for (int e = 0; e < 6; e++) gin[e] = xe[((long long)b * TT + (TT - 1)) * EE + e];
    gin[6] = vol[b];
    for (int j = t; j < 256; j += 128) {
        float s = g1_b[j];
        #pragma unroll
        for (int e = 0; e < 7; e++) s += g1_w[j * 7 + e] * gin[e];
        hid[j] = fmaxf(s, 0.f);
    }
    __syncthreads();
    for (int p = t; p < 96; p += 128) {
        float ai = rh_b[p];
        for (int j = 0; j < 512; j++) ai += xl[j] * rh_w[p * 512 + j];
        float gs = g2_b[p];
        for (int j = 0; j < 256; j++) gs += hid[j] * g2_w[p * 256 + j];
        float gate = 1.f / (1.f + expf(-gs));
        out[b * PP + p] = vol[b] * gp_w[p] + gp_b[p] + gate * ai;
    }
}

// ---------------------------------------------------------------------------
// Launch.  Workspace layout (bytes, total ~147.2 MB):
//   XB   bf16 residual  @ 0           (33554432)
//   Y    fp32 branch    @ 33554432    (67108864)
//   CH   chunk region   @ 100663296   (33554432)
//        WQ (LSTM fp16 weights, 2MB) lives here during the LSTM phase;
//        QKVc @ +0 | SCc @ +12582912 | CTXc @ +29360128 ; HIDc @ +0 [FFN]
//   WB   bf16 weights   @ 134217728   (12582912)
//   VOL                 @ 147193856   (256)
// ---------------------------------------------------------------------------
extern "C" void kernel_launch(void* const* d_in, const int* in_sizes, int n_in,
                              void* d_out, int out_size, void* d_ws, size_t ws_size,
                              hipStream_t stream)
{
    const float* x_enc      = (const float*)d_in[0];
    const float* omega      = (const float*)d_in[4];
    const float* alpha      = (const float*)d_in[5];
    const float* beta       = (const float*)d_in[6];
    const float* gp_w       = (const float*)d_in[7];
    const float* gp_b       = (const float*)d_in[8];
    const float* w_ih       = (const float*)d_in[9];
    const float* w_hh       = (const float*)d_in[10];
    const float* b_ih       = (const float*)d_in[11];
    const float* b_hh       = (const float*)d_in[12];
    const float* attn_in_w  = (const float*)d_in[13];
    const float* attn_in_b  = (const float*)d_in[14];
    const float* attn_out_w = (const float*)d_in[15];
    const float* attn_out_b = (const float*)d_in[16];
    const float* ln1_g      = (const float*)d_in[17];
    const float* ln1_b      = (const float*)d_in[18];
    const float* ffn_w1     = (const float*)d_in[19];
    const float* ffn_b1     = (const float*)d_in[20];
    const float* ffn_w2     = (const float*)d_in[21];
    const float* ffn_b2     = (const float*)d_in[22];
    const float* ln2_g      = (const float*)d_in[23];
    const float* ln2_b      = (const float*)d_in[24];
    const float* rh_w       = (const float*)d_in[25];
    const float* rh_b       = (const float*)d_in[26];
    const float* g1_w       = (const float*)d_in[27];
    const float* g1_b       = (const float*)d_in[28];
    const float* g2_w       = (const float*)d_in[29];
    const float* g2_b       = (const float*)d_in[30];

    char* ws = (char*)d_ws;
    unsigned short* XB   = (unsigned short*)(ws + 0);
    float*          Y    = (float*)(ws + 33554432LL);
    unsigned short* WQ   = (unsigned short*)(ws + 100663296LL);  // 2MB, LSTM phase only
    unsigned short* QKVc = (unsigned short*)(ws + 100663296LL);
    unsigned short* SCc  = (unsigned short*)(ws + 113246208LL);
    unsigned short* CTXc = (unsigned short*)(ws + 130023424LL);
    unsigned short* HIDc = (unsigned short*)(ws + 100663296LL);
    unsigned short* WATI = (unsigned short*)(ws + 134217728LL);
    unsigned short* WATO = WATI + 1572864;
    unsigned short* WF1  = WATI + 2097152;
    unsigned short* WF2  = WATI + 4194304;
    float*          VOL  = (float*)(ws + 147193856LL);

    cvt_k<<<2048, 256, 0, stream>>>(attn_in_w,  WATI, 1572864);
    cvt_k<<<1024, 256, 0, stream>>>(attn_out_w, WATO, 524288);
    cvt_k<<<2048, 256, 0, stream>>>(ffn_w1,     WF1,  2097152);
    cvt_k<<<2048, 256, 0, stream>>>(ffn_w2,     WF2,  2097152);

    garch_k<<<1, 64, 0, stream>>>(x_enc, omega, alpha, beta, VOL);

    wq_prep_k<<<2048, 256, 0, stream>>>(w_hh, (__half2*)WQ);
    lstm_batch_k<<<64, 512, 0, stream>>>(x_enc, WQ, w_ih, b_ih, b_hh, XB);

    for (int l = 0; l < 2; l++) {
        // Attention, chunked over batches: 8 chunks x 8 batches (4096 rows)
        for (int c = 0; c < 8; c++) {
            long long rowOff = (long long)c * 8 * 512;
            gemm_bt<false, true, false, true><<<dim3(32, 12, 1), 256, 0, stream>>>(
                XB + rowOff * 512, 512, 0, 0,
                WATI + l * 786432, 512, 0, 0, attn_in_b + l * 1536,
                QKVc, 1536, 0, 0, 512, 1, 1.0f);
            gemm_bt<false, false, false, true><<<dim3(4, 4, 32), 256, 0, stream>>>(
                QKVc, 1536, 786432LL, 128LL, QKVc + 512, 1536, 786432LL, 128LL, nullptr,
                SCc, 512, 1048576LL, 262144LL, 128, 4, 0.088388347648318447f);
            softmax_k<<<4096, 256, 0, stream>>>(SCc);
            gemm_bt<true, false, false, true><<<dim3(4, 1, 32), 256, 0, stream>>>(
                SCc, 512, 1048576LL, 262144LL, QKVc + 1024, 1536, 786432LL, 128LL, nullptr,
                CTXc, 512, 262144LL, 128LL, 512, 4, 1.0f);
            gemm_bt<false, true, false, false><<<dim3(32, 4, 1), 256, 0, stream>>>(
                CTXc, 512, 0, 0, WATO + l * 262144, 512, 0, 0, attn_out_b + l * 512,
                Y + rowOff * 512, 512, 0, 0, 512, 1, 1.0f);
        }
        ln_k<<<8192, 256, 0, stream>>>(XB, Y, ln1_g + l * 512, ln1_b + l * 512);

        // FFN, chunked over rows: 4 chunks x 8192 rows
        for (int mc = 0; mc < 4; mc++) {
            long long rowOff = (long long)mc * 8192;
            gemm_bt<false, true, true, true><<<dim3(64, 16, 1), 256, 0, stream>>>(
                XB + rowOff * 512, 512, 0, 0,
                WF1 + l * 1048576, 512, 0, 0, ffn_b1 + l * 2048,
                HIDc, 2048, 0, 0, 512, 1, 1.0f);
            gemm_bt<false, true, false, false><<<dim3(64, 4, 1), 256, 0, stream>>>(
                HIDc, 2048, 0, 0, WF2 + l * 1048576, 2048, 0, 0, ffn_b2 + l * 512,
                Y + rowOff * 512, 512, 0, 0, 2048, 1, 1.0f);
        }
        ln_k<<<8192, 256, 0, stream>>>(XB, Y, ln2_g + l * 512, ln2_b + l * 512);
    }

    head_k<<<64, 128, 0, stream>>>(XB, x_enc, VOL, rh_w, rh_b,
                                   g1_w, g1_b, g2_w, g2_b, gp_w, gp_b,
                                   (float*)d_out);
}

// Round 8
// 29501.135 us; speedup vs baseline: 1.4023x; 1.4023x over previous
//
#include <hip/hip_runtime.h>
#include <hip/hip_bf16.h>

// Model dims
#define BB 64
#define TT 512
#define DD 512
#define EE 6
#define PP 96
#define NHH 4
#define HDD 128
#define FFF 2048

#define LSTM_NB 128   // persistent-LSTM grid: 128 blocks (co-residency trivially safe)

typedef short bf16x8 __attribute__((ext_vector_type(8)));
typedef float f32x4 __attribute__((ext_vector_type(4)));

__device__ __forceinline__ float bf2f(unsigned short u) {
    unsigned int x = ((unsigned int)u) << 16;
    return __uint_as_float(x);
}
__device__ __forceinline__ unsigned short f2bf(float f) {
    __hip_bfloat16 h = __float2bfloat16(f);
    return *reinterpret_cast<unsigned short*>(&h);
}

// ---------------------------------------------------------------------------
// Generic MFMA GEMM:  C[m][n] = alpha * sum_k A[m][k] * W[n][k]  (+bias[n])
// 128x128 tile, BK=32, 256 threads (4 waves, each a 64x64 quadrant of
// 4x4 mfma_f32_16x16x32_bf16). TRANSW stages W[k*ldw+n] (V^T for P·V).
// Batched via blockIdx.z -> (b = z/Hdiv, h = z%Hdiv) offsets.
// ---------------------------------------------------------------------------
template<bool TRANSW, bool BIAS, bool RELU, bool OUTBF16>
__global__ __launch_bounds__(256) void gemm_bt(
    const unsigned short* __restrict__ A, int lda, long long aB, long long aH,
    const unsigned short* __restrict__ W, int ldw, long long wB, long long wH,
    const float* __restrict__ bias,
    void* __restrict__ Cv, int ldc, long long cB, long long cH,
    int K, int Hdiv, float alpha)
{
    __shared__ unsigned short As[128 * 40];
    __shared__ unsigned short Ws[128 * 40];
    int t = threadIdx.x;
    int z = blockIdx.z;
    int zb = z / Hdiv, zh = z - zb * Hdiv;
    long long aOff = (long long)zb * aB + (long long)zh * aH;
    long long wOff = (long long)zb * wB + (long long)zh * wH;
    long long cOff = (long long)zb * cB + (long long)zh * cH;
    int m0 = blockIdx.x * 128, n0 = blockIdx.y * 128;

    int arow = t >> 1, acol = (t & 1) * 16;
    const unsigned short* Ag = A + aOff + (long long)(m0 + arow) * lda + acol;
    const unsigned short* WgN = W + wOff + (long long)(n0 + arow) * ldw + acol;
    int wk = t >> 3, wn = (t & 7) * 16;
    const unsigned short* WgT = W + wOff + n0 + wn;

    int wave = t >> 6, lane = t & 63;
    int wm = (wave & 1) * 64, wn2 = (wave >> 1) * 64;
    int lrow = lane & 15, quad = lane >> 4;

    f32x4 acc[4][4];
    #pragma unroll
    for (int i = 0; i < 4; i++)
        #pragma unroll
        for (int j = 0; j < 4; j++)
            acc[i][j] = (f32x4){0.f, 0.f, 0.f, 0.f};

    for (int k0 = 0; k0 < K; k0 += 32) {
        __syncthreads();
        {
            uint4 a0 = *(const uint4*)(Ag + k0);
            uint4 a1 = *(const uint4*)(Ag + k0 + 8);
            *(uint4*)&As[arow * 40 + acol] = a0;
            *(uint4*)&As[arow * 40 + acol + 8] = a1;
            if (!TRANSW) {
                uint4 w0 = *(const uint4*)(WgN + k0);
                uint4 w1 = *(const uint4*)(WgN + k0 + 8);
                *(uint4*)&Ws[arow * 40 + acol] = w0;
                *(uint4*)&Ws[arow * 40 + acol + 8] = w1;
            } else {
                const unsigned short* p = WgT + (long long)(k0 + wk) * ldw;
                uint4 w0 = *(const uint4*)(p);
                uint4 w1 = *(const uint4*)(p + 8);
                const unsigned short* s0 = (const unsigned short*)&w0;
                const unsigned short* s1 = (const unsigned short*)&w1;
                #pragma unroll
                for (int j = 0; j < 8; j++) Ws[(wn + j) * 40 + wk] = s0[j];
                #pragma unroll
                for (int j = 0; j < 8; j++) Ws[(wn + 8 + j) * 40 + wk] = s1[j];
            }
        }
        __syncthreads();
        bf16x8 af[4], bf[4];
        #pragma unroll
        for (int i = 0; i < 4; i++)
            af[i] = *(const bf16x8*)&As[(wm + i * 16 + lrow) * 40 + quad * 8];
        #pragma unroll
        for (int j = 0; j < 4; j++)
            bf[j] = *(const bf16x8*)&Ws[(wn2 + j * 16 + lrow) * 40 + quad * 8];
        #pragma unroll
        for (int i = 0; i < 4; i++)
            #pragma unroll
            for (int j = 0; j < 4; j++)
                acc[i][j] = __builtin_amdgcn_mfma_f32_16x16x32_bf16(af[i], bf[j], acc[i][j], 0, 0, 0);
    }

    #pragma unroll
    for (int i = 0; i < 4; i++) {
        #pragma unroll
        for (int j = 0; j < 4; j++) {
            #pragma unroll
            for (int r = 0; r < 4; r++) {
                int row = m0 + wm + i * 16 + quad * 4 + r;
                int col = n0 + wn2 + j * 16 + lrow;
                float v = acc[i][j][r] * alpha;
                if (BIAS) v += bias[col];
                if (RELU) v = fmaxf(v, 0.f);
                long long idx = cOff + (long long)row * ldc + col;
                if (OUTBF16) ((unsigned short*)Cv)[idx] = f2bf(v);
                else         ((float*)Cv)[idx] = v;
            }
        }
    }
}

// ---------------------------------------------------------------------------
__global__ void cvt_k(const float* __restrict__ in, unsigned short* __restrict__ out, int n)
{
    int i = blockIdx.x * 256 + threadIdx.x;
    int stride = gridDim.x * 256;
    for (; i < n; i += stride) out[i] = f2bf(in[i]);
}

// ---------------------------------------------------------------------------
// GARCH: per-batch variance + 511-step scalar recurrence. 1 block, lane = batch.
// ---------------------------------------------------------------------------
__global__ __launch_bounds__(64) void garch_k(
    const float* __restrict__ xe, const float* __restrict__ omega,
    const float* __restrict__ alpha, const float* __restrict__ beta,
    float* __restrict__ vol)
{
    int b = threadIdx.x;
    float sm = 0.f, sq = 0.f;
    for (int t2 = 0; t2 < TT; t2++) {
        float r = xe[((long long)b * TT + t2) * EE + 5];
        sm += r; sq += r * r;
    }
    float mean = sm / 512.f;
    float var = (sq - 512.f * mean * mean) / 511.f;
    float h = var + 1e-6f;
    float om = log1pf(expf(omega[0]));
    float al = 0.2f / (1.f + expf(-alpha[0]));
    float be = 0.8f / (1.f + expf(-beta[0]));
    for (int t2 = 0; t2 < TT - 1; t2++) {
        float r = xe[((long long)b * TT + t2) * EE + 5];
        h = om + al * r * r + be * h;
    }
    vol[b] = sqrtf(h);
}

// ---------------------------------------------------------------------------
// Persistent d-parallel LSTM, ONE launch, 128 blocks x 256 threads.
// Block owns dims d0..d0+3; wave kq takes K-slice [kq*128, kq*128+128) for
// all 16 (dim,gate) streams; lane = batch. Partials -> LDS; wave kq then
// finalizes dim d0+kq (gate math, c update, h + XB store).
//
// Cross-block exchange goes through the SHARED L3 (Infinity Cache) via
// agent-scope atomics (sc-bit cache bypass) -- per-XCD L2s are never dirtied
// with h, so NO L2 flush/invalidate is needed (this is what made cg::sync
// cost 67us/step in r5). Barrier: monotonic per-block flag prog[blk] = steps
// completed; readers spin with ">= t" + bounded timeout -> stale/poisoned
// flags or lost blocks give a wrong answer, NEVER a hang (r3's failure mode
// is structurally excluded). prog[] zeroed by host memset each call.
// t=0 uses h0=0 (no reads, no spin). h ping-pongs between 2 slots; the
// prog >= t gate makes slot reuse race-free (see step proof in comments).
// ---------------------------------------------------------------------------
__global__ __launch_bounds__(256) void lstm_persist2_k(
    const float* __restrict__ xe, const float* __restrict__ w_hh,
    const float* __restrict__ w_ih, const float* __restrict__ b_ih,
    const float* __restrict__ b_hh,
    float* __restrict__ hbuf,            // 2 x 512 x 64 fp32
    unsigned int* __restrict__ prog,     // LSTM_NB flags
    unsigned short* __restrict__ XB_)
{
    int blk = blockIdx.x;
    int tid = threadIdx.x;
    int kq = tid >> 6, lane = tid & 63;
    int d0 = blk * 4;

    __shared__ float part[4][16][64];

    // wave-uniform weight row pointers: stream j -> dim d0+(j>>2), gate j&3
    const float* wp[16];
    #pragma unroll
    for (int j = 0; j < 16; j++) {
        int dl = j >> 2, g = j & 3;
        wp[j] = w_hh + ((long long)g * 512 + d0 + dl) * 512 + kq * 128;
    }
    // finalize constants for this wave's dim
    int dmy = d0 + kq;
    float wi[4][6], bias[4];
    #pragma unroll
    for (int g = 0; g < 4; g++) {
        #pragma unroll
        for (int e = 0; e < 6; e++) wi[g][e] = w_ih[((long long)g * 512 + dmy) * 6 + e];
        bias[g] = b_ih[g * 512 + dmy] + b_hh[g * 512 + dmy];
    }
    float c = 0.f;
    const float* xb = xe + (long long)lane * TT * EE;
    unsigned short* ob = XB_ + (long long)lane * TT * DD + dmy;

    for (int t = 0; t < 512; t++) {
        float acc[16];
        #pragma unroll
        for (int j = 0; j < 16; j++) acc[j] = 0.f;

        if (t > 0) {
            // barrier: wait until every block has published h(t)
            if (tid < LSTM_NB) {
                int iters = 0;
                while (__hip_atomic_load(&prog[tid], __ATOMIC_ACQUIRE,
                                         __HIP_MEMORY_SCOPE_AGENT) < (unsigned)t) {
                    if (++iters > 20000) break;   // graceful wrong-answer, never hang
                    __builtin_amdgcn_s_sleep(8);
                }
            }
            __syncthreads();
            const float* hs = hbuf + (t & 1) * (512 * 64) + (kq * 128) * 64 + lane;
            #pragma unroll 8
            for (int k = 0; k < 128; k++) {
                float hv = __hip_atomic_load(&hs[k * 64], __ATOMIC_RELAXED,
                                             __HIP_MEMORY_SCOPE_AGENT);
                #pragma unroll
                for (int j = 0; j < 16; j++) acc[j] += hv * wp[j][k];
            }
        }

        #pragma unroll
        for (int j = 0; j < 16; j++) part[kq][j][lane] = acc[j];
        __syncthreads();

        // finalize dim dmy = d0 + kq (all 4 waves, disjoint dims)
        float g4[4];
        #pragma unroll
        for (int g = 0; g < 4; g++)
            g4[g] = part[0][kq * 4 + g][lane] + part[1][kq * 4 + g][lane]
                  + part[2][kq * 4 + g][lane] + part[3][kq * 4 + g][lane];
        const float* xr = xb + t * EE;
        float x0 = xr[0], x1 = xr[1], x2 = xr[2], x3 = xr[3], x4 = xr[4], x5 = xr[5];
        float pi = g4[0] + bias[0] + x0*wi[0][0] + x1*wi[0][1] + x2*wi[0][2] + x3*wi[0][3] + x4*wi[0][4] + x5*wi[0][5];
        float pf = g4[1] + bias[1] + x0*wi[1][0] + x1*wi[1][1] + x2*wi[1][2] + x3*wi[1][3] + x4*wi[1][4] + x5*wi[1][5];
        float pg = g4[2] + bias[2] + x0*wi[2][0] + x1*wi[2][1] + x2*wi[2][2] + x3*wi[2][3] + x4*wi[2][4] + x5*wi[2][5];
        float po = g4[3] + bias[3] + x0*wi[3][0] + x1*wi[3][1] + x2*wi[3][2] + x3*wi[3][3] + x4*wi[3][4] + x5*wi[3][5];
        float ig = 1.f / (1.f + __expf(-pi));
        float fg = 1.f / (1.f + __expf(-pf));
        float gg = tanhf(pg);
        float og = 1.f / (1.f + __expf(-po));
        c = fg * c + ig * gg;
        float hn = og * tanhf(c);

        float* hw = hbuf + ((t + 1) & 1) * (512 * 64) + dmy * 64 + lane;
        __hip_atomic_store(hw, hn, __ATOMIC_RELAXED, __HIP_MEMORY_SCOPE_AGENT);
        ob[t * DD] = f2bf(hn);
        __threadfence();      // order h stores before the flag release (intra-block HB via syncthreads)
        __syncthreads();
        if (tid == 0)
            __hip_atomic_store(&prog[blk], (unsigned)(t + 1), __ATOMIC_RELEASE,
                               __HIP_MEMORY_SCOPE_AGENT);
    }
}

// ---------------------------------------------------------------------------
// Softmax over last dim (512), in-place on bf16 scores. One wave per row.
// ---------------------------------------------------------------------------
__global__ __launch_bounds__(256) void softmax_k(unsigned short* __restrict__ S)
{
    long long row = (long long)blockIdx.x * 4 + (threadIdx.x >> 6);
    int lane = threadIdx.x & 63;
    unsigned short* p = S + row * 512 + lane * 8;
    uint4 raw = *(const uint4*)p;
    unsigned short* u = (unsigned short*)&raw;
    float v[8];
    float m = -1e30f;
    #pragma unroll
    for (int j = 0; j < 8; j++) { v[j] = bf2f(u[j]); m = fmaxf(m, v[j]); }
    #pragma unroll
    for (int off = 1; off < 64; off <<= 1) m = fmaxf(m, __shfl_xor(m, off));
    float s = 0.f;
    #pragma unroll
    for (int j = 0; j < 8; j++) { v[j] = __expf(v[j] - m); s += v[j]; }
    #pragma unroll
    for (int off = 1; off < 64; off <<= 1) s += __shfl_xor(s, off);
    float inv = 1.f / s;
    unsigned int pk[4];
    #pragma unroll
    for (int j = 0; j < 4; j++)
        pk[j] = (unsigned int)f2bf(v[2 * j] * inv) | ((unsigned int)f2bf(v[2 * j + 1] * inv) << 16);
    *(uint4*)p = make_uint4(pk[0], pk[1], pk[2], pk[3]);
}

// ---------------------------------------------------------------------------
// Residual + LayerNorm: XB = LN(XB + Y)*g + b  (bf16 residual stream).
// ---------------------------------------------------------------------------
__global__ __launch_bounds__(256) void ln_k(
    unsigned short* XB_, const float* __restrict__ Y_,
    const float* __restrict__ g, const float* __restrict__ b2)
{
    long long row = (long long)blockIdx.x * 4 + (threadIdx.x >> 6);
    int lane = threadIdx.x & 63;
    long long base = row * 512 + lane * 8;
    float s[8];
    {
        uint4 xr = *(const uint4*)&XB_[base];
        const unsigned short* xu = (const unsigned short*)&xr;
        float4 y0 = *(const float4*)&Y_[base];
        float4 y1 = *(const float4*)&Y_[base + 4];
        s[0] = bf2f(xu[0]) + y0.x; s[1] = bf2f(xu[1]) + y0.y;
        s[2] = bf2f(xu[2]) + y0.z; s[3] = bf2f(xu[3]) + y0.w;
        s[4] = bf2f(xu[4]) + y1.x; s[5] = bf2f(xu[5]) + y1.y;
        s[6] = bf2f(xu[6]) + y1.z; s[7] = bf2f(xu[7]) + y1.w;
    }
    float sm = 0.f, sq = 0.f;
    #pragma unroll
    for (int j = 0; j < 8; j++) { sm += s[j]; sq += s[j] * s[j]; }
    #pragma unroll
    for (int off = 1; off < 64; off <<= 1) {
        sm += __shfl_xor(sm, off);
        sq += __shfl_xor(sq, off);
    }
    float mean = sm * (1.f / 512.f);
    float var = sq * (1.f / 512.f) - mean * mean;
    float rstd = rsqrtf(var + 1e-5f);
    int col = lane * 8;
    float o[8];
    #pragma unroll
    for (int j = 0; j < 8; j++) o[j] = (s[j] - mean) * rstd * g[col + j] + b2[col + j];
    unsigned int pk[4];
    #pragma unroll
    for (int j = 0; j < 4; j++)
        pk[j] = (unsigned int)f2bf(o[2 * j]) | ((unsigned int)f2bf(o[2 * j + 1]) << 16);
    *(uint4*)&XB_[base] = make_uint4(pk[0], pk[1], pk[2], pk[3]);
}

// ---------------------------------------------------------------------------
// Heads: garch_base + gate * ai_residual. One block per batch.
// ---------------------------------------------------------------------------
__global__ __launch_bounds__(128) void head_k(
    const unsigned short* __restrict__ XB_, const float* __restrict__ xe,
    const float* __restrict__ vol,
    const float* __restrict__ rh_w, const float* __restrict__ rh_b,
    const float* __restrict__ g1_w, const float* __restrict__ g1_b,
    const float* __restrict__ g2_w, const float* __restrict__ g2_b,
    const float* __restrict__ gp_w, const float* __restrict__ gp_b,
    float* __restrict__ out)
{
    int b = blockIdx.x, t = threadIdx.x;
    __shared__ float xl[512];
    __shared__ float hid[256];
    for (int j = t; j < 512; j += 128)
        xl[j] = bf2f(XB_[((long long)b * TT + (TT - 1)) * DD + j]);
    float gin[7];
    #pragma unroll
    for (int e = 0; e < 6; e++) gin[e] = xe[((long long)b * TT + (TT - 1)) * EE + e];
    gin[6] = vol[b];
    for (int j = t; j < 256; j += 128) {
        float s = g1_b[j];
        #pragma unroll
        for (int e = 0; e < 7; e++) s += g1_w[j * 7 + e] * gin[e];
        hid[j] = fmaxf(s, 0.f);
    }
    __syncthreads();
    for (int p = t; p < 96; p += 128) {
        float ai = rh_b[p];
        for (int j = 0; j < 512; j++) ai += xl[j] * rh_w[p * 512 + j];
        float gs = g2_b[p];
        for (int j = 0; j < 256; j++) gs += hid[j] * g2_w[p * 256 + j];
        float gate = 1.f / (1.f + expf(-gs));
        out[b * PP + p] = vol[b] * gp_w[p] + gp_b[p] + gate * ai;
    }
}

// ---------------------------------------------------------------------------
// Launch.  Workspace layout (bytes, total ~147.2 MB):
//   XB   bf16 residual  @ 0           (33554432)
//   Y    fp32 branch    @ 33554432    (67108864)
//   CH   chunk region   @ 100663296   (33554432)
//        QKVc @ +0 | SCc @ +12582912 | CTXc @ +29360128 ; HIDc @ +0 [FFN]
//   WB   bf16 weights   @ 134217728   (12582912)
//   HBUF (2x512x64 f32) @ 146800640   (262144)
//   VOL                 @ 147193856   (256)
//   PROG                @ 147194112   (512)
// ---------------------------------------------------------------------------
extern "C" void kernel_launch(void* const* d_in, const int* in_sizes, int n_in,
                              void* d_out, int out_size, void* d_ws, size_t ws_size,
                              hipStream_t stream)
{
    const float* x_enc      = (const float*)d_in[0];
    const float* omega      = (const float*)d_in[4];
    const float* alpha      = (const float*)d_in[5];
    const float* beta       = (const float*)d_in[6];
    const float* gp_w       = (const float*)d_in[7];
    const float* gp_b       = (const float*)d_in[8];
    const float* w_ih       = (const float*)d_in[9];
    const float* w_hh       = (const float*)d_in[10];
    const float* b_ih       = (const float*)d_in[11];
    const float* b_hh       = (const float*)d_in[12];
    const float* attn_in_w  = (const float*)d_in[13];
    const float* attn_in_b  = (const float*)d_in[14];
    const float* attn_out_w = (const float*)d_in[15];
    const float* attn_out_b = (const float*)d_in[16];
    const float* ln1_g      = (const float*)d_in[17];
    const float* ln1_b      = (const float*)d_in[18];
    const float* ffn_w1     = (const float*)d_in[19];
    const float* ffn_b1     = (const float*)d_in[20];
    const float* ffn_w2     = (const float*)d_in[21];
    const float* ffn_b2     = (const float*)d_in[22];
    const float* ln2_g      = (const float*)d_in[23];
    const float* ln2_b      = (const float*)d_in[24];
    const float* rh_w       = (const float*)d_in[25];
    const float* rh_b       = (const float*)d_in[26];
    const float* g1_w       = (const float*)d_in[27];
    const float* g1_b       = (const float*)d_in[28];
    const float* g2_w       = (const float*)d_in[29];
    const float* g2_b       = (const float*)d_in[30];

    char* ws = (char*)d_ws;
    unsigned short* XB   = (unsigned short*)(ws + 0);
    float*          Y    = (float*)(ws + 33554432LL);
    unsigned short* QKVc = (unsigned short*)(ws + 100663296LL);
    unsigned short* SCc  = (unsigned short*)(ws + 113246208LL);
    unsigned short* CTXc = (unsigned short*)(ws + 130023424LL);
    unsigned short* HIDc = (unsigned short*)(ws + 100663296LL);
    unsigned short* WATI = (unsigned short*)(ws + 134217728LL);
    unsigned short* WATO = WATI + 1572864;
    unsigned short* WF1  = WATI + 2097152;
    unsigned short* WF2  = WATI + 4194304;
    float*          HBUF = (float*)(ws + 146800640LL);
    float*          VOL  = (float*)(ws + 147193856LL);
    unsigned int*   PROG = (unsigned int*)(ws + 147194112LL);

    hipMemsetAsync(PROG, 0, LSTM_NB * sizeof(unsigned int), stream);

    cvt_k<<<2048, 256, 0, stream>>>(attn_in_w,  WATI, 1572864);
    cvt_k<<<1024, 256, 0, stream>>>(attn_out_w, WATO, 524288);
    cvt_k<<<2048, 256, 0, stream>>>(ffn_w1,     WF1,  2097152);
    cvt_k<<<2048, 256, 0, stream>>>(ffn_w2,     WF2,  2097152);

    garch_k<<<1, 64, 0, stream>>>(x_enc, omega, alpha, beta, VOL);

    lstm_persist2_k<<<LSTM_NB, 256, 0, stream>>>(x_enc, w_hh, w_ih, b_ih, b_hh,
                                                 HBUF, PROG, XB);

    for (int l = 0; l < 2; l++) {
        // Attention, chunked over batches: 8 chunks x 8 batches (4096 rows)
        for (int c = 0; c < 8; c++) {
            long long rowOff = (long long)c * 8 * 512;
            gemm_bt<false, true, false, true><<<dim3(32, 12, 1), 256, 0, stream>>>(
                XB + rowOff * 512, 512, 0, 0,
                WATI + l * 786432, 512, 0, 0, attn_in_b + l * 1536,
                QKVc, 1536, 0, 0, 512, 1, 1.0f);
            gemm_bt<false, false, false, true><<<dim3(4, 4, 32), 256, 0, stream>>>(
                QKVc, 1536, 786432LL, 128LL, QKVc + 512, 1536, 786432LL, 128LL, nullptr,
                SCc, 512, 1048576LL, 262144LL, 128, 4, 0.088388347648318447f);
            softmax_k<<<4096, 256, 0, stream>>>(SCc);
            gemm_bt<true, false, false, true><<<dim3(4, 1, 32), 256, 0, stream>>>(
                SCc, 512, 1048576LL, 262144LL, QKVc + 1024, 1536, 786432LL, 128LL, nullptr,
                CTXc, 512, 262144LL, 128LL, 512, 4, 1.0f);
            gemm_bt<false, true, false, false><<<dim3(32, 4, 1), 256, 0, stream>>>(
                CTXc, 512, 0, 0, WATO + l * 262144, 512, 0, 0, attn_out_b + l * 512,
                Y + rowOff * 512, 512, 0, 0, 512, 1, 1.0f);
        }
        ln_k<<<8192, 256, 0, stream>>>(XB, Y, ln1_g + l * 512, ln1_b + l * 512);

        // FFN, chunked over rows: 4 chunks x 8192 rows
        for (int mc = 0; mc < 4; mc++) {
            long long rowOff = (long long)mc * 8192;
            gemm_bt<false, true, true, true><<<dim3(64, 16, 1), 256, 0, stream>>>(
                XB + rowOff * 512, 512, 0, 0,
                WF1 + l * 1048576, 512, 0, 0, ffn_b1 + l * 2048,
                HIDc, 2048, 0, 0, 512, 1, 1.0f);
            gemm_bt<false, true, false, false><<<dim3(64, 4, 1), 256, 0, stream>>>(
                HIDc, 2048, 0, 0, WF2 + l * 1048576, 2048, 0, 0, ffn_b2 + l * 512,
                Y + rowOff * 512, 512, 0, 0, 2048, 1, 1.0f);
        }
        ln_k<<<8192, 256, 0, stream>>>(XB, Y, ln2_g + l * 512, ln2_b + l * 512);
    }

    head_k<<<64, 128, 0, stream>>>(XB, x_enc, VOL, rh_w, rh_b,
                                   g1_w, g1_b, g2_w, g2_b, gp_w, gp_b,
                                   (float*)d_out);
}